// Round 1
// 204.904 us; speedup vs baseline: 1.0397x; 1.0397x over previous
//
#include <hip/hip_runtime.h>

// Problem constants (fixed by setup_inputs in the reference)
#define S_SPK 2
#define B_BATCH 4
#define M_MIC 4
#define W_TAP 3
#define F_FREQ 257
#define T_TIME 512
#define C_CH 4
#define FT (F_FREQ * T_TIME)      // 131584

// ws layout: float L[S][S][B]  index (so*S_SPK + st)*B_BATCH + b  -> 16 floats

__global__ void zero_ws_kernel(float* ws) {
    if (threadIdx.x < 16) ws[threadIdx.x] = 0.0f;
}

// Grid: x = ceil(F/4) = 65 (4 f-rows per block, one per wave), y = S*B = 8.
// Each wave owns one f-row: 64 lanes x 8 t = 512 = T. Halo (t0-1 / t0+8) via shuffle.
__global__ __launch_bounds__(256) void pit_main_kernel(
    const float* __restrict__ masks,   // [S,B,M,W,F,T,2]
    const float* __restrict__ mixr,    // [S,B,M,F,T]
    const float* __restrict__ mixi,    // [S,B,M,F,T]
    const float* __restrict__ tgtr,    // [S,B,C,F,T] (use c=0)
    const float* __restrict__ tgti,    // [S,B,C,F,T]
    float* __restrict__ ws)
{
    const int sb   = blockIdx.y;            // so*B + b
    const int so   = sb / B_BATCH;
    const int b    = sb % B_BATCH;
    const int wave = threadIdx.x >> 6;
    const int lane = threadIdx.x & 63;
    const int f    = blockIdx.x * 4 + wave; // one f-row per wave
    const int t0   = lane << 3;             // 8 consecutive t per lane

    float L0 = 0.0f, L1 = 0.0f;

    if (f < F_FREQ) {   // wave-uniform predicate: shuffles below are safe
        const long rowOff = (long)f * T_TIME + t0;

        // ---- mix window values: mv[m][k] = mix[m][f][t0-1+k], k = 0..9 ----
        float mvr[M_MIC][10], mvi[M_MIC][10];
        const long mixSB = (long)sb * M_MIC * FT;
        #pragma unroll
        for (int m = 0; m < M_MIC; ++m) {
            const float* mr = mixr + mixSB + (long)m * FT + rowOff;
            const float* mi = mixi + mixSB + (long)m * FT + rowOff;
            const float4 r0 = *(const float4*)(mr);
            const float4 r1 = *(const float4*)(mr + 4);
            const float4 i0 = *(const float4*)(mi);
            const float4 i1 = *(const float4*)(mi + 4);
            // halo from neighbor lanes (wave covers the full T row contiguously)
            float rl = __shfl_up(r1.w, 1, 64);
            float il = __shfl_up(i1.w, 1, 64);
            float rr = __shfl_down(r0.x, 1, 64);
            float ir = __shfl_down(i0.x, 1, 64);
            if (lane == 0)  { rl = 0.0f; il = 0.0f; }   // t = -1 (zero pad)
            if (lane == 63) { rr = 0.0f; ir = 0.0f; }   // t = 512 (zero pad)
            mvr[m][0] = rl;   mvi[m][0] = il;
            mvr[m][1] = r0.x; mvi[m][1] = i0.x;
            mvr[m][2] = r0.y; mvi[m][2] = i0.y;
            mvr[m][3] = r0.z; mvi[m][3] = i0.z;
            mvr[m][4] = r0.w; mvi[m][4] = i0.w;
            mvr[m][5] = r1.x; mvi[m][5] = i1.x;
            mvr[m][6] = r1.y; mvi[m][6] = i1.y;
            mvr[m][7] = r1.z; mvi[m][7] = i1.z;
            mvr[m][8] = r1.w; mvi[m][8] = i1.w;
            mvr[m][9] = rr;   mvi[m][9] = ir;
        }

        float orr[8], oii[8];
        #pragma unroll
        for (int t = 0; t < 8; ++t) { orr[t] = 0.0f; oii[t] = 0.0f; }

        // ---- masks: 12 independent float4-quad groups, fully unrolled ----
        const long mskSB = (long)sb * M_MIC;
        #pragma unroll
        for (int m = 0; m < M_MIC; ++m) {
            #pragma unroll
            for (int w = 0; w < W_TAP; ++w) {
                const float* mp = masks +
                    ((((mskSB + m) * W_TAP + w) * F_FREQ + f) * (long)T_TIME + t0) * 2;
                const float4 q0 = *(const float4*)(mp);       // t0,t0+1 (re,im)
                const float4 q1 = *(const float4*)(mp + 4);   // t0+2,t0+3
                const float4 q2 = *(const float4*)(mp + 8);   // t0+4,t0+5
                const float4 q3 = *(const float4*)(mp + 12);  // t0+6,t0+7
                // out[t] += mix[t-1+w] * mask[w][t]   (complex MAC); mv[t+w]
                orr[0] += mvr[m][0+w]*q0.x - mvi[m][0+w]*q0.y;
                oii[0] += mvr[m][0+w]*q0.y + mvi[m][0+w]*q0.x;
                orr[1] += mvr[m][1+w]*q0.z - mvi[m][1+w]*q0.w;
                oii[1] += mvr[m][1+w]*q0.w + mvi[m][1+w]*q0.z;
                orr[2] += mvr[m][2+w]*q1.x - mvi[m][2+w]*q1.y;
                oii[2] += mvr[m][2+w]*q1.y + mvi[m][2+w]*q1.x;
                orr[3] += mvr[m][3+w]*q1.z - mvi[m][3+w]*q1.w;
                oii[3] += mvr[m][3+w]*q1.w + mvi[m][3+w]*q1.z;
                orr[4] += mvr[m][4+w]*q2.x - mvi[m][4+w]*q2.y;
                oii[4] += mvr[m][4+w]*q2.y + mvi[m][4+w]*q2.x;
                orr[5] += mvr[m][5+w]*q2.z - mvi[m][5+w]*q2.w;
                oii[5] += mvr[m][5+w]*q2.w + mvi[m][5+w]*q2.z;
                orr[6] += mvr[m][6+w]*q3.x - mvi[m][6+w]*q3.y;
                oii[6] += mvr[m][6+w]*q3.y + mvi[m][6+w]*q3.x;
                orr[7] += mvr[m][7+w]*q3.z - mvi[m][7+w]*q3.w;
                oii[7] += mvr[m][7+w]*q3.w + mvi[m][7+w]*q3.z;
            }
        }

        // ---- targets (channel 0), both candidate speakers ----
        const long tIdx0 = ((long)(0 * B_BATCH + b) * C_CH + 0) * FT + rowOff;
        const long tIdx1 = ((long)(1 * B_BATCH + b) * C_CH + 0) * FT + rowOff;
        float tr0[8], ti0[8], tr1[8], ti1[8];
        *(float4*)&tr0[0] = *(const float4*)(tgtr + tIdx0);
        *(float4*)&tr0[4] = *(const float4*)(tgtr + tIdx0 + 4);
        *(float4*)&ti0[0] = *(const float4*)(tgti + tIdx0);
        *(float4*)&ti0[4] = *(const float4*)(tgti + tIdx0 + 4);
        *(float4*)&tr1[0] = *(const float4*)(tgtr + tIdx1);
        *(float4*)&tr1[4] = *(const float4*)(tgtr + tIdx1 + 4);
        *(float4*)&ti1[0] = *(const float4*)(tgti + tIdx1);
        *(float4*)&ti1[4] = *(const float4*)(tgti + tIdx1 + 4);

        #pragma unroll
        for (int t = 0; t < 8; ++t) {
            const float ao = sqrtf(orr[t]*orr[t] + oii[t]*oii[t]);
            const float a0 = sqrtf(tr0[t]*tr0[t] + ti0[t]*ti0[t]);
            const float a1 = sqrtf(tr1[t]*tr1[t] + ti1[t]*ti1[t]);
            L0 += fabsf(tr0[t] - orr[t]) + fabsf(ti0[t] - oii[t]) + fabsf(a0 - ao);
            L1 += fabsf(tr1[t] - orr[t]) + fabsf(ti1[t] - oii[t]) + fabsf(a1 - ao);
        }
    }

    // wave(64) shuffle reduction (runs for all waves; idle waves contribute 0)
    #pragma unroll
    for (int off = 32; off > 0; off >>= 1) {
        L0 += __shfl_down(L0, off, 64);
        L1 += __shfl_down(L1, off, 64);
    }
    __shared__ float s0[4], s1[4];
    if (lane == 0) { s0[wave] = L0; s1[wave] = L1; }
    __syncthreads();
    if (threadIdx.x == 0) {
        atomicAdd(&ws[(so * S_SPK + 0) * B_BATCH + b], s0[0] + s0[1] + s0[2] + s0[3]);
        atomicAdd(&ws[(so * S_SPK + 1) * B_BATCH + b], s1[0] + s1[1] + s1[2] + s1[3]);
    }
}

__global__ void pit_final_kernel(const float* __restrict__ ws,
                                 float* __restrict__ out, int num_utts) {
    if (threadIdx.x == 0 && blockIdx.x == 0) {
        float acc = 0.0f;
        for (int b = 0; b < B_BATCH; ++b) {
            // perm (0,1): L[0][0] + L[1][1];  perm (1,0): L[0][1] + L[1][0]
            const float pid = ws[(0 * S_SPK + 0) * B_BATCH + b] + ws[(1 * S_SPK + 1) * B_BATCH + b];
            const float psw = ws[(0 * S_SPK + 1) * B_BATCH + b] + ws[(1 * S_SPK + 0) * B_BATCH + b];
            const float sc0 = 3.0f * pid / (float)S_SPK;
            const float sc1 = 3.0f * psw / (float)S_SPK;
            acc += fminf(sc0, sc1);
        }
        out[0] = acc / (float)num_utts;
    }
}

extern "C" void kernel_launch(void* const* d_in, const int* in_sizes, int n_in,
                              void* d_out, int out_size, void* d_ws, size_t ws_size,
                              hipStream_t stream) {
    const float* masks = (const float*)d_in[0];
    const float* mixr  = (const float*)d_in[1];
    const float* mixi  = (const float*)d_in[2];
    const float* tgtr  = (const float*)d_in[3];
    const float* tgti  = (const float*)d_in[4];
    // input_sizes values are never used by the reference; only its length is.
    const int num_utts = in_sizes[5];

    float* ws  = (float*)d_ws;
    float* out = (float*)d_out;

    zero_ws_kernel<<<1, 64, 0, stream>>>(ws);

    dim3 grid((F_FREQ + 3) / 4, S_SPK * B_BATCH);   // (65, 8)
    pit_main_kernel<<<grid, 256, 0, stream>>>(masks, mixr, mixi, tgtr, tgti, ws);

    pit_final_kernel<<<1, 64, 0, stream>>>(ws, out, num_utts);
}